// Round 1
// baseline (432.175 us; speedup 1.0000x reference)
//
#include <hip/hip_runtime.h>

// Problem geometry: x is (F=64, A=128, C=2, N=4096) fp32.
// rows = F*A*C = 16384 independent signals of length 4096.
// Each row -> 1x3 conv -> 4094 outputs, weights chosen by channel (row & 1).
// Output layout: flat (row * 4094 + n), matching merged.reshape(F, -1).

#define N_IN 4096
#define N_OUT 4094
#define CHUNKS_PER_ROW 1024   // ceil(4094 / 4); last chunk has 2 valid outputs
#define ROWS 16384            // 64 * 128 * 2

__global__ __launch_bounds__(256) void RTGRFID_51539607553079_kernel(
    const float* __restrict__ x,
    const float* __restrict__ w_rssi,  const float* __restrict__ b_rssi,
    const float* __restrict__ w_phase, const float* __restrict__ b_phase,
    float* __restrict__ out)
{
    const unsigned tid = blockIdx.x * blockDim.x + threadIdx.x;  // < 16M, fits u32
    const int row   = tid >> 10;          // / CHUNKS_PER_ROW
    const int chunk = tid & 1023;
    const int n     = chunk << 2;

    // Channel is uniform within a block (256 | 1024): no divergence, and the
    // weight loads become wave-uniform broadcasts out of L1.
    const int ch = row & 1;
    const float w0 = ch ? w_phase[0] : w_rssi[0];
    const float w1 = ch ? w_phase[1] : w_rssi[1];
    const float w2 = ch ? w_phase[2] : w_rssi[2];
    const float b  = ch ? b_phase[0] : b_rssi[0];

    // Input row base is 16 KiB-aligned -> float4 loads are aligned.
    const float4* in4 = (const float4*)(x + (long long)row * N_IN);
    const float4 a = in4[chunk];                 // s[n .. n+3]

    float s4 = 0.f, s5 = 0.f;
    if (chunk < CHUNKS_PER_ROW - 1) {            // halo from next chunk
        const float4 nb = in4[chunk + 1];        // s[n+4 .. n+7]
        s4 = nb.x; s5 = nb.y;
    }

    const float o0 = fmaf(w0, a.x, fmaf(w1, a.y, fmaf(w2, a.z, b)));
    const float o1 = fmaf(w0, a.y, fmaf(w1, a.z, fmaf(w2, a.w, b)));
    const float o2 = fmaf(w0, a.z, fmaf(w1, a.w, fmaf(w2, s4, b)));
    const float o3 = fmaf(w0, a.w, fmaf(w1, s4, fmaf(w2, s5, b)));

    // Output row stride 4094: row*4094 + n is always even -> float2 stores
    // are 8 B-aligned on every row (float4 would misalign on odd rows).
    float2* out2 = (float2*)(out + (long long)row * N_OUT + n);
    out2[0] = make_float2(o0, o1);
    if (chunk < CHUNKS_PER_ROW - 1) {
        out2[1] = make_float2(o2, o3);
    }
    // chunk == 1023: n = 4092, only outputs 4092/4093 exist; both computed
    // entirely from `a` (s[4092..4095]), so the skipped halo load is unused.
}

extern "C" void kernel_launch(void* const* d_in, const int* in_sizes, int n_in,
                              void* d_out, int out_size, void* d_ws, size_t ws_size,
                              hipStream_t stream) {
    const float* x       = (const float*)d_in[0];
    const float* w_rssi  = (const float*)d_in[1];
    const float* b_rssi  = (const float*)d_in[2];
    const float* w_phase = (const float*)d_in[3];
    const float* b_phase = (const float*)d_in[4];
    float* out = (float*)d_out;

    const unsigned total_threads = ROWS * CHUNKS_PER_ROW;   // 16,777,216
    const unsigned block = 256;
    const unsigned grid = total_threads / block;            // 65,536

    RTGRFID_51539607553079_kernel<<<grid, block, 0, stream>>>(
        x, w_rssi, b_rssi, w_phase, b_phase, out);
}